// Round 1
// baseline (1889.208 us; speedup 1.0000x reference)
//
#include <hip/hip_runtime.h>

// Problem constants
#define BATCH   4096
#define NF      39          // num_field
#define ED      16          // embedding size
#define IN_DIM  624         // NF*ED
#define H1N     128
#define H2N     128
#define NXTN    64          // H1N/2
#define DW      400
#define BN_EPS  1e-5f

// ---------------------------------------------------------------------------
// Kernel 1: embedding gather -> flat[B][624], plus linear_part[b] = flat.lw + lb
// ---------------------------------------------------------------------------
__global__ __launch_bounds__(256) void k_gather(const int* __restrict__ idx,
    const float* __restrict__ emb, const float* __restrict__ lw,
    const float* __restrict__ lb, float* __restrict__ flat,
    float* __restrict__ lp) {
  int b = blockIdx.x, t = threadIdx.x;
  __shared__ int si[NF];
  if (t < NF) si[t] = idx[b * NF + t];
  __syncthreads();
  float acc = 0.f;
#pragma unroll
  for (int i = 0; i < 3; i++) {
    int e = t + i * 256;
    if (e < IN_DIM) {
      float v = emb[(size_t)si[e >> 4] * ED + (e & 15)];
      flat[(size_t)b * IN_DIM + e] = v;
      acc = fmaf(v, lw[e], acc);
    }
  }
#pragma unroll
  for (int k = 1; k < 64; k <<= 1) acc += __shfl_xor(acc, k);
  __shared__ float r4[4];
  if ((t & 63) == 0) r4[t >> 6] = acc;
  __syncthreads();
  if (t == 0) lp[b] = r4[0] + r4[1] + r4[2] + r4[3] + lb[0];
}

// ---------------------------------------------------------------------------
// Kernel 2: CIN layer 1.
// h1[b,o,d] = relu( sum_{h,m} W1[o,h,m] x[b,h,d] x[b,m,d] + b1[o] )
// o <  64 -> store to nxt[b][o][d]
// o >= 64 -> res[b][o-64] = sum_d h1
// One block = 4 samples; one wave = 64 lanes = 4 samples x 16 d; each wave
// sweeps a 32-wide o range (wave-uniform W address -> scalar loads).
// ---------------------------------------------------------------------------
__global__ __launch_bounds__(256) void k_cin1(const float* __restrict__ flat,
    const float* __restrict__ w1, const float* __restrict__ b1,
    float* __restrict__ nxt, float* __restrict__ res) {
  __shared__ float xs[4 * IN_DIM];
  int t = threadIdx.x;
  int b0 = blockIdx.x * 4;
  for (int e = t; e < 4 * IN_DIM; e += 256) {
    int bl = e / IN_DIM, r = e - bl * IN_DIM;
    xs[e] = flat[(size_t)(b0 + bl) * IN_DIM + r];
  }
  __syncthreads();
  int lane = t & 63;
  int wid = __builtin_amdgcn_readfirstlane(t >> 6);
  int bb = lane >> 4, d = lane & 15;
  int b = b0 + bb;
  float xr[NF];
#pragma unroll
  for (int m = 0; m < NF; m++) xr[m] = xs[bb * IN_DIM + m * 16 + d];

  for (int oi = 0; oi < 32; oi++) {
    int o = wid * 32 + oi;
    const float* wo = w1 + (size_t)o * (NF * NF);
    float acc0 = 0.f, acc1 = 0.f;
#pragma unroll
    for (int h = 0; h < NF; h++) {
      float s0 = 0.f, s1 = 0.f;
#pragma unroll
      for (int m = 0; m < NF - 1; m += 2) {
        s0 = fmaf(wo[h * NF + m],     xr[m],     s0);
        s1 = fmaf(wo[h * NF + m + 1], xr[m + 1], s1);
      }
      s0 = fmaf(wo[h * NF + NF - 1], xr[NF - 1], s0);
      float sh = s0 + s1;
      if (h & 1) acc1 = fmaf(xr[h], sh, acc1);
      else       acc0 = fmaf(xr[h], sh, acc0);
    }
    float v = fmaxf(acc0 + acc1 + b1[o], 0.f);
    if (o < NXTN) {
      nxt[((size_t)b * NXTN + o) * 16 + d] = v;
    } else {
      v += __shfl_xor(v, 1); v += __shfl_xor(v, 2);
      v += __shfl_xor(v, 4); v += __shfl_xor(v, 8);
      if (d == 0) res[(size_t)b * 192 + (o - NXTN)] = v;
    }
  }
}

// ---------------------------------------------------------------------------
// Kernel 3: CIN layer 2.
// h2[b,o,d] = relu( sum_{h<64,m<39} W2[o,h,m] nxt[b,h,d] x[b,m,d] + b2[o] )
// res[b][64+o] = sum_d h2
// ---------------------------------------------------------------------------
__global__ __launch_bounds__(256) void k_cin2(const float* __restrict__ flat,
    const float* __restrict__ nxt, const float* __restrict__ w2,
    const float* __restrict__ b2, float* __restrict__ res) {
  __shared__ float xs[4 * IN_DIM];
  __shared__ float ns[4 * 1024];
  int t = threadIdx.x;
  int b0 = blockIdx.x * 4;
  for (int e = t; e < 4 * IN_DIM; e += 256) {
    int bl = e / IN_DIM, r = e - bl * IN_DIM;
    xs[e] = flat[(size_t)(b0 + bl) * IN_DIM + r];
  }
  for (int e = t; e < 4 * 1024; e += 256) {
    int bl = e >> 10, r = e & 1023;
    ns[e] = nxt[(size_t)(b0 + bl) * 1024 + r];
  }
  __syncthreads();
  int lane = t & 63;
  int wid = __builtin_amdgcn_readfirstlane(t >> 6);
  int bb = lane >> 4, d = lane & 15;
  int b = b0 + bb;
  float xr[NF];
#pragma unroll
  for (int m = 0; m < NF; m++) xr[m] = xs[bb * IN_DIM + m * 16 + d];
  const float* nsp = ns + bb * 1024 + d;

  for (int oi = 0; oi < 32; oi++) {
    int o = wid * 32 + oi;
    const float* wo = w2 + (size_t)o * (NXTN * NF);
    float acc0 = 0.f, acc1 = 0.f;
#pragma unroll
    for (int h = 0; h < NXTN; h++) {
      float s0 = 0.f, s1 = 0.f;
#pragma unroll
      for (int m = 0; m < NF - 1; m += 2) {
        s0 = fmaf(wo[h * NF + m],     xr[m],     s0);
        s1 = fmaf(wo[h * NF + m + 1], xr[m + 1], s1);
      }
      s0 = fmaf(wo[h * NF + NF - 1], xr[NF - 1], s0);
      float nh = nsp[h * 16];
      if (h & 1) acc1 = fmaf(nh, s0 + s1, acc1);
      else       acc0 = fmaf(nh, s0 + s1, acc0);
    }
    float v = fmaxf(acc0 + acc1 + b2[o], 0.f);
    v += __shfl_xor(v, 1); v += __shfl_xor(v, 2);
    v += __shfl_xor(v, 4); v += __shfl_xor(v, 8);
    if (d == 0) res[(size_t)b * 192 + 64 + o] = v;
  }
}

// ---------------------------------------------------------------------------
// Tiled fp32 GEMM: C[M][N] = op(A)[M][K] * Bm[K][N] + bias[N]
// BN_A: A element transformed as relu(a*bnS[k] + bnSh[k]) (fused BN1+ReLU).
// 64x64 tile, 256 threads, 4x4 microtile, K-tile 16.
// ---------------------------------------------------------------------------
template <bool BN_A>
__global__ __launch_bounds__(256) void k_gemm(const float* __restrict__ A,
    const float* __restrict__ Bm, const float* __restrict__ bias,
    const float* __restrict__ bnS, const float* __restrict__ bnSh,
    float* __restrict__ C, int M, int N, int K) {
  __shared__ float As[64][17];
  __shared__ float Bs[16][65];
  int t = threadIdx.x;
  int tx = t & 15, ty = t >> 4;
  int R = blockIdx.x * 64, C0 = blockIdx.y * 64;
  float acc[4][4] = {};
  for (int k0 = 0; k0 < K; k0 += 16) {
#pragma unroll
    for (int i = 0; i < 4; i++) {
      int idx = t + 256 * i;
      int r = idx >> 4, kk = idx & 15;
      float v = A[(size_t)(R + r) * K + k0 + kk];
      if (BN_A) v = fmaxf(fmaf(v, bnS[k0 + kk], bnSh[k0 + kk]), 0.f);
      As[r][kk] = v;
      int kb = idx >> 6, c = idx & 63;
      int col = C0 + c;
      Bs[kb][c] = (col < N) ? Bm[(size_t)(k0 + kb) * N + col] : 0.f;
    }
    __syncthreads();
#pragma unroll
    for (int kk = 0; kk < 16; kk++) {
      float a[4], bv[4];
#pragma unroll
      for (int i = 0; i < 4; i++) a[i] = As[ty * 4 + i][kk];
#pragma unroll
      for (int j = 0; j < 4; j++) bv[j] = Bs[kk][tx * 4 + j];
#pragma unroll
      for (int i = 0; i < 4; i++)
#pragma unroll
        for (int j = 0; j < 4; j++) acc[i][j] = fmaf(a[i], bv[j], acc[i][j]);
    }
    __syncthreads();
  }
#pragma unroll
  for (int i = 0; i < 4; i++) {
    int r = R + ty * 4 + i;
#pragma unroll
    for (int j = 0; j < 4; j++) {
      int col = C0 + tx * 4 + j;
      if (col < N) C[(size_t)r * N + col] = acc[i][j] + bias[col];
    }
  }
}

// ---------------------------------------------------------------------------
// BN statistics per column (biased variance, training mode) -> fused scale/shift
// ---------------------------------------------------------------------------
__global__ __launch_bounds__(256) void k_bnstats(const float* __restrict__ Y,
    const float* __restrict__ g, const float* __restrict__ bt,
    float* __restrict__ sc, float* __restrict__ sh, int N) {
  int c = blockIdx.x, t = threadIdx.x;
  float s = 0.f, s2 = 0.f;
  for (int r = t; r < BATCH; r += 256) {
    float v = Y[(size_t)r * N + c];
    s += v; s2 = fmaf(v, v, s2);
  }
#pragma unroll
  for (int k = 1; k < 64; k <<= 1) { s += __shfl_xor(s, k); s2 += __shfl_xor(s2, k); }
  __shared__ float rs[4], rs2[4];
  if ((t & 63) == 0) { rs[t >> 6] = s; rs2[t >> 6] = s2; }
  __syncthreads();
  if (t == 0) {
    s = rs[0] + rs[1] + rs[2] + rs[3];
    s2 = rs2[0] + rs2[1] + rs2[2] + rs2[3];
    float m = s * (1.f / BATCH);
    float var = s2 * (1.f / BATCH) - m * m;
    float scl = g[c] * rsqrtf(var + BN_EPS);
    sc[c] = scl;
    sh[c] = bt[c] - m * scl;
  }
}

// ---------------------------------------------------------------------------
// Final: out[b] = [lp | res(192) | relu(bn2(y2))(400)] . out_w + out_b
// One wave per row.
// ---------------------------------------------------------------------------
__global__ __launch_bounds__(256) void k_final(const float* __restrict__ lp,
    const float* __restrict__ res, const float* __restrict__ y2,
    const float* __restrict__ sc2, const float* __restrict__ sh2,
    const float* __restrict__ ow, const float* __restrict__ ob,
    float* __restrict__ out) {
  int t = threadIdx.x;
  int lane = t & 63, w = t >> 6;
  int b = blockIdx.x * 4 + w;
  float acc = 0.f;
  for (int j = lane; j < 593; j += 64) {
    float v;
    if (j == 0)       v = lp[b];
    else if (j < 193) v = res[(size_t)b * 192 + (j - 1)];
    else {
      int c = j - 193;
      v = fmaxf(fmaf(y2[(size_t)b * DW + c], sc2[c], sh2[c]), 0.f);
    }
    acc = fmaf(v, ow[j], acc);
  }
#pragma unroll
  for (int k = 1; k < 64; k <<= 1) acc += __shfl_xor(acc, k);
  if (lane == 0) out[b] = acc + ob[0];
}

// ---------------------------------------------------------------------------
extern "C" void kernel_launch(void* const* d_in, const int* in_sizes, int n_in,
                              void* d_out, int out_size, void* d_ws, size_t ws_size,
                              hipStream_t stream) {
  const int*   feat_index = (const int*)d_in[0];
  // d_in[1] = feat_value: unused by the reference
  const float* emb = (const float*)d_in[2];
  const float* lw  = (const float*)d_in[3];
  const float* lb  = (const float*)d_in[4];
  const float* w1  = (const float*)d_in[5];
  const float* b1  = (const float*)d_in[6];
  const float* w2  = (const float*)d_in[7];
  const float* b2  = (const float*)d_in[8];
  const float* dw1 = (const float*)d_in[9];
  const float* db1 = (const float*)d_in[10];
  const float* g1  = (const float*)d_in[11];
  const float* bb1 = (const float*)d_in[12];
  const float* dw2 = (const float*)d_in[13];
  const float* db2 = (const float*)d_in[14];
  const float* g2  = (const float*)d_in[15];
  const float* bb2 = (const float*)d_in[16];
  const float* ow  = (const float*)d_in[17];
  const float* ob  = (const float*)d_in[18];

  float* ws   = (float*)d_ws;
  float* flat = ws;                    // 4096*624  = 2,555,904 f
  float* nxt  = ws + 2555904;          // 4096*1024 = 4,194,304 f
  float* res  = ws + 6750208;          // 4096*192  =   786,432 f
  float* lp   = ws + 7536640;          // 4096 f
  float* bn1s = ws + 7540736;          // 400
  float* bn1b = bn1s + 400;            // 400
  float* bn2s = bn1b + 400;            // 400
  float* bn2b = bn2s + 400;            // 400  (end: 7,542,336 f = 30.2 MB)
  float* y1   = nxt;                   // alias: nxt dead after k_cin2
  float* y2   = flat;                  // alias: flat dead after first GEMM
  float* out  = (float*)d_out;

  k_gather<<<BATCH, 256, 0, stream>>>(feat_index, emb, lw, lb, flat, lp);
  k_cin1<<<BATCH / 4, 256, 0, stream>>>(flat, w1, b1, nxt, res);
  k_cin2<<<BATCH / 4, 256, 0, stream>>>(flat, nxt, w2, b2, res);
  k_gemm<false><<<dim3(BATCH / 64, 7), 256, 0, stream>>>(
      flat, dw1, db1, nullptr, nullptr, y1, BATCH, DW, IN_DIM);
  k_bnstats<<<DW, 256, 0, stream>>>(y1, g1, bb1, bn1s, bn1b, DW);
  k_gemm<true><<<dim3(BATCH / 64, 7), 256, 0, stream>>>(
      y1, dw2, db2, bn1s, bn1b, y2, BATCH, DW, DW);
  k_bnstats<<<DW, 256, 0, stream>>>(y2, g2, bb2, bn2s, bn2b, DW);
  k_final<<<BATCH / 4, 256, 0, stream>>>(lp, res, y2, bn2s, bn2b, ow, ob, out);
}

// Round 2
// 431.245 us; speedup vs baseline: 4.3808x; 4.3808x over previous
//
#include <hip/hip_runtime.h>

// Problem constants
#define BATCH   4096
#define NF      39          // num_field
#define ED      16          // embedding size
#define IN_DIM  624         // NF*ED
#define DW      400
#define BN_EPS  1e-5f
#define KTOT    2496        // K = 39 m * 64 h (h padded for layer 1)
#define NKSG    78          // KTOT/32 ksteps

typedef __attribute__((ext_vector_type(8))) short short8;
typedef __attribute__((ext_vector_type(4))) float f32x4;
typedef unsigned short u16;

__device__ inline unsigned pack2_trunc(float a, float b) {
  return (__float_as_uint(a) >> 16) | (__float_as_uint(b) & 0xffff0000u);
}
__device__ inline unsigned bf16_rne(float f) {
  unsigned u = __float_as_uint(f);
  u += 0x7fff + ((u >> 16) & 1);
  return u >> 16;
}

// ---------------------------------------------------------------------------
// Kernel 1: embedding gather -> flat[B][624], plus linear_part[b]
// ---------------------------------------------------------------------------
__global__ __launch_bounds__(256) void k_gather(const int* __restrict__ idx,
    const float* __restrict__ emb, const float* __restrict__ lw,
    const float* __restrict__ lb, float* __restrict__ flat,
    float* __restrict__ lp) {
  int b = blockIdx.x, t = threadIdx.x;
  __shared__ int si[NF];
  if (t < NF) si[t] = idx[b * NF + t];
  __syncthreads();
  float acc = 0.f;
#pragma unroll
  for (int i = 0; i < 3; i++) {
    int e = t + i * 256;
    if (e < IN_DIM) {
      float v = emb[(size_t)si[e >> 4] * ED + (e & 15)];
      flat[(size_t)b * IN_DIM + e] = v;
      acc = fmaf(v, lw[e], acc);
    }
  }
#pragma unroll
  for (int k = 1; k < 64; k <<= 1) acc += __shfl_xor(acc, k);
  __shared__ float r4[4];
  if ((t & 63) == 0) r4[t >> 6] = acc;
  __syncthreads();
  if (t == 0) lp[b] = r4[0] + r4[1] + r4[2] + r4[3] + lb[0];
}

// ---------------------------------------------------------------------------
// Wpack prep: Wpack[ksg][n][kk] bf16, k = ksg*32+kk, h = k&63, m = k>>6.
// Layer1: W1[n][h][m] (h<39 else 0); Layer2: W2[n][h][m] (h<64).
// Element offset for B-frag lane: ksg*4096 + n*32 + kk  (kk = quad*8+j).
// ---------------------------------------------------------------------------
__global__ __launch_bounds__(256) void k_prep(const float* __restrict__ w1,
    const float* __restrict__ w2, u16* __restrict__ wp1, u16* __restrict__ wp2) {
  int e = blockIdx.x * 256 + threadIdx.x;
  if (e >= NKSG * 128 * 32) return;
  int ksg = e >> 12, r = e & 4095, n = r >> 5, kk = r & 31;
  int k = ksg * 32 + kk, h = k & 63, m = k >> 6;
  float v1 = (h < NF) ? w1[(size_t)n * (NF * NF) + h * NF + m] : 0.f;
  float v2 = w2[(size_t)n * (64 * NF) + h * NF + m];
  wp1[e] = (u16)bf16_rne(v1);
  wp2[e] = (u16)bf16_rne(v2);
}

// ---------------------------------------------------------------------------
// CIN via MFMA.  GEMM rows = (b,d), cols = o (128), K = (m,h) = 2496.
// A[(b,d)][m*64+h] = s1[h,d] * x[m,d]   (s1 = x for layer1, nxt for layer2)
// Per wave: 4 samples (4 M-tiles of 16 d-rows) x 8 N-tiles, acc 4x8x4 f32.
// s1 values live in registers (lane needs only its quad's h-ranges);
// A-fragments are built in-register; B-fragments stream from L2 (Wpack).
// No LDS, no barriers.
// Layer1: o<64 -> nxt_out[b][d][o] bf16 (A-ready layout); o>=64 -> res[b][o-64]
// Layer2: all o -> res[b][64+o]
// ---------------------------------------------------------------------------
template <bool LAY2>
__global__ __launch_bounds__(256, 2) void k_cin_mfma(
    const float* __restrict__ flat, const u16* __restrict__ nxtg,
    const u16* __restrict__ wp, const float* __restrict__ bias,
    u16* __restrict__ nxt_out, float* __restrict__ res) {
  int t = threadIdx.x;
  int w = t >> 6, lane = t & 63;
  int nl = lane & 15, q = lane >> 4;
  int d = nl;                          // A-row within M-tile = embedding dim
  int b0 = blockIdx.x * 16 + w * 4;    // 4 samples per wave

  // s1 registers: nxr[si][ks][w4] = packed bf16 pair, h = ks*32+q*8+2*w4(+1)
  unsigned nxr[4][2][4];
  if (LAY2) {
#pragma unroll
    for (int si = 0; si < 4; si++)
#pragma unroll
      for (int ks = 0; ks < 2; ks++) {
        uint4 v = *(const uint4*)(nxtg +
            (((size_t)(b0 + si) * 16 + d) * 64 + ks * 32 + q * 8));
        nxr[si][ks][0] = v.x; nxr[si][ks][1] = v.y;
        nxr[si][ks][2] = v.z; nxr[si][ks][3] = v.w;
      }
  } else {
#pragma unroll
    for (int si = 0; si < 4; si++)
#pragma unroll
      for (int ks = 0; ks < 2; ks++)
#pragma unroll
        for (int w4 = 0; w4 < 4; w4++) {
          int h0 = ks * 32 + q * 8 + 2 * w4;
          int h1 = h0 + 1;
          float f0 = (h0 < NF) ? flat[(size_t)(b0 + si) * IN_DIM + h0 * 16 + d] : 0.f;
          float f1 = (h1 < NF) ? flat[(size_t)(b0 + si) * IN_DIM + h1 * 16 + d] : 0.f;
          nxr[si][ks][w4] = pack2_trunc(f0, f1);
        }
  }

  f32x4 acc[4][8];
#pragma unroll
  for (int si = 0; si < 4; si++)
#pragma unroll
    for (int nt = 0; nt < 8; nt++) acc[si][nt] = (f32x4){0.f, 0.f, 0.f, 0.f};

  for (int m = 0; m < NF; m++) {
    float xv[4];
#pragma unroll
    for (int si = 0; si < 4; si++)
      xv[si] = flat[(size_t)(b0 + si) * IN_DIM + m * 16 + d];
#pragma unroll
    for (int ks = 0; ks < 2; ks++) {
      int ksg = m * 2 + ks;
      const u16* wb = wp + (size_t)ksg * 4096 + nl * 32 + q * 8;
      short8 bfr[8];
#pragma unroll
      for (int nt = 0; nt < 8; nt++)
        bfr[nt] = *(const short8*)(wb + nt * 512);   // n-tile stride 16*32
      short8 afr[4];
#pragma unroll
      for (int si = 0; si < 4; si++) {
        union { unsigned u[4]; short8 s; } a;
#pragma unroll
        for (int w4 = 0; w4 < 4; w4++) {
          unsigned u = nxr[si][ks][w4];
          float lo = __uint_as_float(u << 16) * xv[si];
          float hi = __uint_as_float(u & 0xffff0000u) * xv[si];
          a.u[w4] = pack2_trunc(lo, hi);
        }
        afr[si] = a.s;
      }
#pragma unroll
      for (int nt = 0; nt < 8; nt++)
#pragma unroll
        for (int si = 0; si < 4; si++)
          acc[si][nt] = __builtin_amdgcn_mfma_f32_16x16x32_bf16(
              afr[si], bfr[nt], acc[si][nt], 0, 0, 0);
    }
  }

  // Epilogue. C layout: col o = nl, row d = q*4 + r.
#pragma unroll
  for (int si = 0; si < 4; si++) {
    int b = b0 + si;
#pragma unroll
    for (int nt = 0; nt < 8; nt++) {
      int o = nt * 16 + nl;
      float bi = bias[o];
      if (!LAY2 && nt < 4) {
#pragma unroll
        for (int r = 0; r < 4; r++) {
          float v = fmaxf(acc[si][nt][r] + bi, 0.f);
          nxt_out[((size_t)b * 16 + q * 4 + r) * 64 + o] = (u16)bf16_rne(v);
        }
      } else {
        float s = 0.f;
#pragma unroll
        for (int r = 0; r < 4; r++) s += fmaxf(acc[si][nt][r] + bi, 0.f);
        s += __shfl_xor(s, 16);
        s += __shfl_xor(s, 32);
        if (q == 0) {
          int ri = LAY2 ? (64 + o) : (o - 64);
          res[(size_t)b * 192 + ri] = s;
        }
      }
    }
  }
}

// ---------------------------------------------------------------------------
// Tiled fp32 GEMM (deep tower), optionally fusing BN+ReLU on A.
// ---------------------------------------------------------------------------
template <bool BN_A>
__global__ __launch_bounds__(256) void k_gemm(const float* __restrict__ A,
    const float* __restrict__ Bm, const float* __restrict__ bias,
    const float* __restrict__ bnS, const float* __restrict__ bnSh,
    float* __restrict__ C, int M, int N, int K) {
  __shared__ float As[64][17];
  __shared__ float Bs[16][65];
  int t = threadIdx.x;
  int tx = t & 15, ty = t >> 4;
  int R = blockIdx.x * 64, C0 = blockIdx.y * 64;
  float acc[4][4] = {};
  for (int k0 = 0; k0 < K; k0 += 16) {
#pragma unroll
    for (int i = 0; i < 4; i++) {
      int idx = t + 256 * i;
      int r = idx >> 4, kk = idx & 15;
      float v = A[(size_t)(R + r) * K + k0 + kk];
      if (BN_A) v = fmaxf(fmaf(v, bnS[k0 + kk], bnSh[k0 + kk]), 0.f);
      As[r][kk] = v;
      int kb = idx >> 6, c = idx & 63;
      int col = C0 + c;
      Bs[kb][c] = (col < N) ? Bm[(size_t)(k0 + kb) * N + col] : 0.f;
    }
    __syncthreads();
#pragma unroll
    for (int kk = 0; kk < 16; kk++) {
      float a[4], bv[4];
#pragma unroll
      for (int i = 0; i < 4; i++) a[i] = As[ty * 4 + i][kk];
#pragma unroll
      for (int j = 0; j < 4; j++) bv[j] = Bs[kk][tx * 4 + j];
#pragma unroll
      for (int i = 0; i < 4; i++)
#pragma unroll
        for (int j = 0; j < 4; j++) acc[i][j] = fmaf(a[i], bv[j], acc[i][j]);
    }
    __syncthreads();
  }
#pragma unroll
  for (int i = 0; i < 4; i++) {
    int r = R + ty * 4 + i;
#pragma unroll
    for (int j = 0; j < 4; j++) {
      int col = C0 + tx * 4 + j;
      if (col < N) C[(size_t)r * N + col] = acc[i][j] + bias[col];
    }
  }
}

// ---------------------------------------------------------------------------
// BN statistics per column -> fused scale/shift
// ---------------------------------------------------------------------------
__global__ __launch_bounds__(256) void k_bnstats(const float* __restrict__ Y,
    const float* __restrict__ g, const float* __restrict__ bt,
    float* __restrict__ sc, float* __restrict__ sh, int N) {
  int c = blockIdx.x, t = threadIdx.x;
  float s = 0.f, s2 = 0.f;
  for (int r = t; r < BATCH; r += 256) {
    float v = Y[(size_t)r * N + c];
    s += v; s2 = fmaf(v, v, s2);
  }
#pragma unroll
  for (int k = 1; k < 64; k <<= 1) { s += __shfl_xor(s, k); s2 += __shfl_xor(s2, k); }
  __shared__ float rs[4], rs2[4];
  if ((t & 63) == 0) { rs[t >> 6] = s; rs2[t >> 6] = s2; }
  __syncthreads();
  if (t == 0) {
    s = rs[0] + rs[1] + rs[2] + rs[3];
    s2 = rs2[0] + rs2[1] + rs2[2] + rs2[3];
    float m = s * (1.f / BATCH);
    float var = s2 * (1.f / BATCH) - m * m;
    float scl = g[c] * rsqrtf(var + BN_EPS);
    sc[c] = scl;
    sh[c] = bt[c] - m * scl;
  }
}

// ---------------------------------------------------------------------------
// Final concat + dot
// ---------------------------------------------------------------------------
__global__ __launch_bounds__(256) void k_final(const float* __restrict__ lp,
    const float* __restrict__ res, const float* __restrict__ y2,
    const float* __restrict__ sc2, const float* __restrict__ sh2,
    const float* __restrict__ ow, const float* __restrict__ ob,
    float* __restrict__ out) {
  int t = threadIdx.x;
  int lane = t & 63, w = t >> 6;
  int b = blockIdx.x * 4 + w;
  float acc = 0.f;
  for (int j = lane; j < 593; j += 64) {
    float v;
    if (j == 0)       v = lp[b];
    else if (j < 193) v = res[(size_t)b * 192 + (j - 1)];
    else {
      int c = j - 193;
      v = fmaxf(fmaf(y2[(size_t)b * DW + c], sc2[c], sh2[c]), 0.f);
    }
    acc = fmaf(v, ow[j], acc);
  }
#pragma unroll
  for (int k = 1; k < 64; k <<= 1) acc += __shfl_xor(acc, k);
  if (lane == 0) out[b] = acc + ob[0];
}

// ---------------------------------------------------------------------------
extern "C" void kernel_launch(void* const* d_in, const int* in_sizes, int n_in,
                              void* d_out, int out_size, void* d_ws, size_t ws_size,
                              hipStream_t stream) {
  const int*   feat_index = (const int*)d_in[0];
  const float* emb = (const float*)d_in[2];
  const float* lw  = (const float*)d_in[3];
  const float* lb  = (const float*)d_in[4];
  const float* w1  = (const float*)d_in[5];
  const float* b1  = (const float*)d_in[6];
  const float* w2  = (const float*)d_in[7];
  const float* b2  = (const float*)d_in[8];
  const float* dw1 = (const float*)d_in[9];
  const float* db1 = (const float*)d_in[10];
  const float* g1  = (const float*)d_in[11];
  const float* bb1 = (const float*)d_in[12];
  const float* dw2 = (const float*)d_in[13];
  const float* db2 = (const float*)d_in[14];
  const float* g2  = (const float*)d_in[15];
  const float* bb2 = (const float*)d_in[16];
  const float* ow  = (const float*)d_in[17];
  const float* ob  = (const float*)d_in[18];

  float* ws   = (float*)d_ws;
  float* flat = ws;                        // 4096*624 = 2,555,904 f
  float* y1   = ws + 2555904;              // 4096*400 = 1,638,400 f
  float* res  = ws + 4194304;              // 4096*192 =   786,432 f
  float* lp   = ws + 4980736;              // 4096 f
  float* bn1s = ws + 4984832;              // 400
  float* bn1b = bn1s + 400;
  float* bn2s = bn1b + 400;
  float* bn2b = bn2s + 400;                // ends 4,986,432 f
  u16*  nxtg  = (u16*)(ws + 4986432);      // 4096*16*64 bf16 = 2,097,152 f
  u16*  wp1   = (u16*)(ws + 7083584);      // 319,488 bf16 = 159,744 f
  u16*  wp2   = (u16*)(ws + 7243328);      // 319,488 bf16 -> ends 7,403,072 f (29.6 MB)
  float* y2   = flat;                      // alias: flat dead after GEMM1+CIN
  float* out  = (float*)d_out;

  k_gather<<<BATCH, 256, 0, stream>>>(feat_index, emb, lw, lb, flat, lp);
  k_prep<<<(NKSG * 128 * 32 + 255) / 256, 256, 0, stream>>>(w1, w2, wp1, wp2);
  k_cin_mfma<false><<<BATCH / 16, 256, 0, stream>>>(flat, nullptr, wp1, b1, nxtg, res);
  k_cin_mfma<true><<<BATCH / 16, 256, 0, stream>>>(flat, nxtg, wp2, b2, nullptr, res);
  k_gemm<false><<<dim3(BATCH / 64, 7), 256, 0, stream>>>(
      flat, dw1, db1, nullptr, nullptr, y1, BATCH, DW, IN_DIM);
  k_bnstats<<<DW, 256, 0, stream>>>(y1, g1, bb1, bn1s, bn1b, DW);
  k_gemm<true><<<dim3(BATCH / 64, 7), 256, 0, stream>>>(
      y1, dw2, db2, bn1s, bn1b, y2, BATCH, DW, DW);
  k_bnstats<<<DW, 256, 0, stream>>>(y2, g2, bb2, bn2s, bn2b, DW);
  k_final<<<BATCH / 4, 256, 0, stream>>>(lp, res, y2, bn2s, bn2b, ow, ob, out);
}